// Round 10
// baseline (227.605 us; speedup 1.0000x reference)
//
#include <hip/hip_runtime.h>
#include <hip/hip_bf16.h>
#include <math.h>

// Problem constants: B=2, S=2048, D=1024, H=16, HD=64
typedef unsigned short ushort_t;
typedef unsigned char uchar_t;
typedef __attribute__((ext_vector_type(8))) short short8;   // 8 bf16 = 4 VGPRs (MFMA A/B frag)
typedef __attribute__((ext_vector_type(4))) float f32x4;    // MFMA C/D frag

struct __align__(8) us4 { ushort_t u[4]; };

__device__ __forceinline__ ushort_t f2bf(float x) {
  union { float f; unsigned u; } c; c.f = x;
  unsigned r = c.u + 0x7FFFu + ((c.u >> 16) & 1u);  // RNE
  return (ushort_t)(r >> 16);
}
__device__ __forceinline__ float bf2f(ushort_t b) {
  union { unsigned u; float f; } c; c.u = ((unsigned)b) << 16;
  return c.f;
}

// ---------------------------------------------------------------------------
// fp32 -> bf16 bulk convert (green verbatim; four launches)
// ---------------------------------------------------------------------------
__global__ __launch_bounds__(256) void cvt_kernel(const float* __restrict__ src,
                                                  ushort_t* __restrict__ dst, int n) {
  int i = (blockIdx.x * 256 + threadIdx.x) * 4;
  if (i < n) {
    f32x4 v = *(const f32x4*)(src + i);
    us4 o;
    o.u[0] = f2bf(v[0]); o.u[1] = f2bf(v[1]); o.u[2] = f2bf(v[2]); o.u[3] = f2bf(v[3]);
    *(us4*)(dst + i) = o;
  }
}

// ---------------------------------------------------------------------------
// QKV projection GEMM (green verbatim). K output (z==1) stored with the
// hd-unit XOR swizzle: hd' = ((hd>>3)^(s&7))*8+(hd&7). Q,V linear bf16.
// ---------------------------------------------------------------------------
struct QkvArgs {
  const ushort_t* X;
  const ushort_t* W0; const ushort_t* W1; const ushort_t* W2;
  const float* b0; const float* b1; const float* b2;
  ushort_t* o0; ushort_t* o1; ushort_t* o2;
};

__global__ __launch_bounds__(256) void qkv_gemm(QkvArgs a) {
  __shared__ __align__(16) ushort_t As[128 * 32];
  __shared__ __align__(16) ushort_t Bs[128 * 32];
  const int z = blockIdx.z;
  const ushort_t* W  = (z == 0) ? a.W0 : ((z == 1) ? a.W1 : a.W2);
  const float* bias  = (z == 0) ? a.b0 : ((z == 1) ? a.b1 : a.b2);
  ushort_t* out      = (z == 0) ? a.o0 : ((z == 1) ? a.o1 : a.o2);
  const int swz = (z == 1) ? 7 : 0;   // hd-unit swizzle mask (K only)
  const int mBase = blockIdx.x * 128;
  const int nBase = blockIdx.y * 128;
  const int tid  = threadIdx.x;
  const int lane = tid & 63;
  const int w    = tid >> 6;
  const int wm   = w >> 1, wn = w & 1;
  const int quad = lane >> 4;
  const int l15  = lane & 15;

  f32x4 acc[4][4] = {};

  const int srow = lane >> 2;
  const int scol = (lane & 3) * 8;
  const ushort_t* gA0 = a.X + (mBase + srow) * 1024 + scol;
  const ushort_t* gB0 = W   + (nBase + srow) * 1024 + scol;

  for (int k0 = 0; k0 < 1024; k0 += 32) {
#pragma unroll
    for (int p = 0; p < 2; ++p) {
      int rr = (w * 2 + p) * 16;
      __builtin_amdgcn_global_load_lds(
          (const __attribute__((address_space(1))) void*)(gA0 + rr * 1024 + k0),
          (__attribute__((address_space(3))) void*)(As + (w * 2 + p) * 512), 16, 0, 0);
      __builtin_amdgcn_global_load_lds(
          (const __attribute__((address_space(1))) void*)(gB0 + rr * 1024 + k0),
          (__attribute__((address_space(3))) void*)(Bs + (w * 2 + p) * 512), 16, 0, 0);
    }
    __syncthreads();
    short8 af[4], bfr[4];
#pragma unroll
    for (int mi = 0; mi < 4; ++mi)
      af[mi] = *(const short8*)(As + (wm * 64 + mi * 16 + l15) * 32 + quad * 8);
#pragma unroll
    for (int ni = 0; ni < 4; ++ni)
      bfr[ni] = *(const short8*)(Bs + (wn * 64 + ni * 16 + l15) * 32 + quad * 8);
#pragma unroll
    for (int mi = 0; mi < 4; ++mi)
#pragma unroll
      for (int ni = 0; ni < 4; ++ni)
        acc[mi][ni] = __builtin_amdgcn_mfma_f32_16x16x32_bf16(af[mi], bfr[ni], acc[mi][ni], 0, 0, 0);
    __syncthreads();
  }

#pragma unroll
  for (int ni = 0; ni < 4; ++ni) {
    int n = nBase + wn * 64 + ni * 16 + l15;
    float bv = bias[n];
    int h = n >> 6, hd = n & 63;
    int hdHi = hd >> 3, hdLo = hd & 7;
#pragma unroll
    for (int mi = 0; mi < 4; ++mi) {
      int m0 = mBase + wm * 64 + mi * 16 + quad * 4;
#pragma unroll
      for (int r = 0; r < 4; ++r) {
        int m = m0 + r;
        int bb = m >> 11, s = m & 2047;
        int hdw = (((hdHi ^ (s & swz)) << 3) | hdLo);
        out[((bb * 16 + h) * 2048 + s) * 64 + hdw] = f2bf(acc[mi][ni][r] + bv);
      }
    }
  }
}

// ---------------------------------------------------------------------------
// V transpose + fp8 convert (green verbatim): bf16 [bh][s][hd] -> e4m3
// [bh][hd][s] with key-unit XOR swizzle within each 128-key tile.
// ---------------------------------------------------------------------------
__global__ __launch_bounds__(256) void tr_kernel(const ushort_t* __restrict__ vb,
                                                 uchar_t* __restrict__ vT) {
  __shared__ uchar_t Ls[64 * 68];
  int bh = blockIdx.y;
  int s0 = blockIdx.x * 64;
  int tid = threadIdx.x;
  const ushort_t* vp = vb + (size_t)bh * 131072;
  uchar_t* op = vT + (size_t)bh * 131072;
#pragma unroll
  for (int p = 0; p < 2; ++p) {
    int c = p * 256 + tid;
    int row = c >> 3, u = c & 7;
    short8 x = *(const short8*)(vp + (size_t)(s0 + row) * 64 + u * 8);
    float f0 = bf2f((ushort_t)x[0]), f1 = bf2f((ushort_t)x[1]);
    float f2 = bf2f((ushort_t)x[2]), f3 = bf2f((ushort_t)x[3]);
    float f4 = bf2f((ushort_t)x[4]), f5 = bf2f((ushort_t)x[5]);
    float f6 = bf2f((ushort_t)x[6]), f7 = bf2f((ushort_t)x[7]);
    unsigned int lo = __builtin_amdgcn_cvt_pk_fp8_f32(f0, f1, 0, false);
    lo = __builtin_amdgcn_cvt_pk_fp8_f32(f2, f3, lo, true);
    unsigned int hi = __builtin_amdgcn_cvt_pk_fp8_f32(f4, f5, 0, false);
    hi = __builtin_amdgcn_cvt_pk_fp8_f32(f6, f7, hi, true);
    *(unsigned int*)(Ls + row * 68 + u * 8)     = lo;
    *(unsigned int*)(Ls + row * 68 + u * 8 + 4) = hi;
  }
  __syncthreads();
#pragma unroll
  for (int p = 0; p < 4; ++p) {
    int oc = p * 256 + tid;
    int hd = oc >> 4, sc = oc & 15;
    unsigned int v = 0;
#pragma unroll
    for (int i = 0; i < 4; ++i)
      v |= ((unsigned int)Ls[(sc * 4 + i) * 68 + hd]) << (8 * i);
    int u = ((s0 & 64) >> 4) + (sc >> 2);          // key 16B-unit within 128-tile
    int dest = (s0 & ~127) + ((u ^ (hd & 7)) * 16) + (sc & 3) * 4;
    *(unsigned int*)(op + (size_t)hd * 2048 + dest) = v;
  }
}

// ---------------------------------------------------------------------------
// Attention — r7 green source with ONE delta: double-buffered K/V staging.
// Prologue stages tile 0 -> buf0. Per tile: ONE __syncthreads (drains this
// tile's DMA via vmcnt, and guarantees the other buffer's readers are done),
// THEN issue next tile's DMA into the other buffer (overlaps this tile's
// compute), then compute. Inner compute/swizzles/numerics byte-identical to
// r7; only the buffer base (uniform offset) and loop skeleton changed.
// LDS: 2x16K (Ks) + 2x8K (Vt) + 16K (Ps) = 64 KB.
// ---------------------------------------------------------------------------
__global__ __launch_bounds__(256) void attn_kernel(const ushort_t* __restrict__ qb,
                                                   const ushort_t* __restrict__ kb,
                                                   const uchar_t* __restrict__ vT,
                                                   ushort_t* __restrict__ zb) {
  __shared__ __align__(16) ushort_t Ks[2][128 * 64];   // [buf][key][hd] swizzled bf16
  __shared__ __align__(16) uchar_t  Vt[2][64 * 128];   // [buf][hd][key] swizzled fp8
  __shared__ __align__(16) uchar_t  Ps[128 * 128];     // [q][key] swizzled fp8 (wave-private rows)
  const int bh   = blockIdx.y;
  const int qblk = blockIdx.x * 128;
  const int tid  = threadIdx.x;
  const int lane = tid & 63;
  const int w    = tid >> 6;
  const int quad = lane >> 4;
  const int l15  = lane & 15;
  const int l7   = l15 & 7;
  const float cexp = 0.02209708691f * 1.44269504089f;  // (1/sqrt(2048)) * log2(e)

  const ushort_t* qpage = qb + (size_t)bh * (2048 * 64);
  const ushort_t* kpage = kb + (size_t)bh * (2048 * 64);
  const uchar_t*  vpage = vT + (size_t)bh * (64 * 2048);

  // Q fragments (constant across key tiles; Q global layout is linear)
  short8 qf[2][2];
#pragma unroll
  for (int nb = 0; nb < 2; ++nb) {
    int qg = qblk + w * 32 + nb * 16 + l15;
#pragma unroll
    for (int kd = 0; kd < 2; ++kd)
      qf[nb][kd] = *(const short8*)(qpage + (size_t)qg * 64 + kd * 32 + quad * 8);
  }

  float psum[2] = {0.f, 0.f};
  f32x4 o[4][2] = {};  // O^T: [hd block][q block]

  // ---- prologue: stage tile 0 into buffer 0 ----
#pragma unroll
  for (int p = 0; p < 4; ++p) {
    int j = w * 4 + p;
    __builtin_amdgcn_global_load_lds(
        (const __attribute__((address_space(1))) void*)(kpage + (size_t)j * 512 + lane * 8),
        (__attribute__((address_space(3))) void*)(Ks[0] + j * 512), 16, 0, 0);
  }
  if (127 >= qblk) {  // needV(kt=0)
#pragma unroll
    for (int p = 0; p < 2; ++p) {
      int j = w * 2 + p;
      __builtin_amdgcn_global_load_lds(
          (const __attribute__((address_space(1))) void*)(vpage + (size_t)(j * 8 + (lane >> 3)) * 2048 + (lane & 7) * 16),
          (__attribute__((address_space(3))) void*)(Vt[0] + j * 1024), 16, 0, 0);
    }
  }

  for (int kt2 = 0; kt2 < 2048; kt2 += 256) {
#pragma unroll
    for (int ph = 0; ph < 2; ++ph) {
      const int kt = kt2 + ph * 128;
      const ushort_t* KsB = Ks[ph];
      const uchar_t*  VtB = Vt[ph];
      const bool needP = (kt + 127 >= qblk + w * 32);   // wave-uniform

      __syncthreads();  // drains tile-kt DMA (vmcnt) + buffer ph^1 readers done

      // ---- issue next tile's DMA into the other buffer (overlaps compute) ----
      const int ktn = kt + 128;
      if (ktn < 2048) {
#pragma unroll
        for (int p = 0; p < 4; ++p) {
          int j = w * 4 + p;
          __builtin_amdgcn_global_load_lds(
              (const __attribute__((address_space(1))) void*)(kpage + (size_t)ktn * 64 + j * 512 + lane * 8),
              (__attribute__((address_space(3))) void*)(Ks[ph ^ 1] + j * 512), 16, 0, 0);
        }
        if (ktn + 127 >= qblk) {  // needV(ktn)
#pragma unroll
          for (int p = 0; p < 2; ++p) {
            int j = w * 2 + p;
            __builtin_amdgcn_global_load_lds(
                (const __attribute__((address_space(1))) void*)(vpage + (size_t)(j * 8 + (lane >> 3)) * 2048 + ktn + (lane & 7) * 16),
                (__attribute__((address_space(3))) void*)(Vt[ph ^ 1] + j * 1024), 16, 0, 0);
          }
        }
      }

      // ---- S^T = K*Q^T per 16-key slice; exp + psum + fp8 P pack ----
#pragma unroll
      for (int mb = 0; mb < 8; ++mb) {
        const ushort_t* krow = KsB + (mb * 16 + l15) * 64;
        short8 kf0 = *(const short8*)(krow + ((0 + quad) ^ l7) * 8);
        short8 kf1 = *(const short8*)(krow + ((4 + quad) ^ l7) * 8);
        f32x4 s0 = {}, s1 = {};
        s0 = __builtin_amdgcn_mfma_f32_16x16x32_bf16(kf0, qf[0][0], s0, 0, 0, 0);
        s0 = __builtin_amdgcn_mfma_f32_16x16x32_bf16(kf1, qf[0][1], s0, 0, 0, 0);
        s1 = __builtin_amdgcn_mfma_f32_16x16x32_bf16(kf0, qf[1][0], s1, 0, 0, 0);
        s1 = __builtin_amdgcn_mfma_f32_16x16x32_bf16(kf1, qf[1][1], s1, 0, 0, 0);
        const int keyb = kt + mb * 16 + quad * 4;
#pragma unroll
        for (int nb = 0; nb < 2; ++nb) {
          f32x4 s = nb ? s1 : s0;
          float p0 = __builtin_amdgcn_exp2f(s[0] * cexp);
          float p1 = __builtin_amdgcn_exp2f(s[1] * cexp);
          float p2 = __builtin_amdgcn_exp2f(s[2] * cexp);
          float p3 = __builtin_amdgcn_exp2f(s[3] * cexp);
          psum[nb] += (p0 + p1) + (p2 + p3);  // denominator: ALL keys (mask is post-softmax)
          if (needP) {
            int qg = qblk + w * 32 + nb * 16 + l15;
            float m0 = (keyb + 0 >= qg) ? p0 : 0.f;
            float m1 = (keyb + 1 >= qg) ? p1 : 0.f;
            float m2 = (keyb + 2 >= qg) ? p2 : 0.f;
            float m3 = (keyb + 3 >= qg) ? p3 : 0.f;
            unsigned int pk = __builtin_amdgcn_cvt_pk_fp8_f32(m0, m1, 0, false);
            pk = __builtin_amdgcn_cvt_pk_fp8_f32(m2, m3, pk, true);
            *(unsigned int*)(Ps + (w * 32 + nb * 16 + l15) * 128 + ((mb ^ l7) * 16) + quad * 4) = pk;
          }
        }
      }

      // ---- O^T += V^T * P^T in fp8 (skip fully-masked tiles) ----
      if (needP) {
#pragma unroll
        for (int kd = 0; kd < 4; ++kd) {
          const int un = ((kd * 2 + (quad >> 1)) ^ l7) * 16 + (quad & 1) * 8;
          long long pf0 = *(const long long*)(Ps + (w * 32 + l15) * 128 + un);
          long long pf1 = *(const long long*)(Ps + (w * 32 + 16 + l15) * 128 + un);
#pragma unroll
          for (int mb = 0; mb < 4; ++mb) {
            long long vf = *(const long long*)(VtB + (mb * 16 + l15) * 128 + un);
            o[mb][0] = __builtin_amdgcn_mfma_f32_16x16x32_fp8_fp8(vf, pf0, o[mb][0], 0, 0, 0);
            o[mb][1] = __builtin_amdgcn_mfma_f32_16x16x32_fp8_fp8(vf, pf1, o[mb][1], 0, 0, 0);
          }
        }
      }
    }
  }

  // ---- final denominator reduce (across quads) + store ----
#pragma unroll
  for (int nb = 0; nb < 2; ++nb) {
    psum[nb] += __shfl_xor(psum[nb], 16, 64);
    psum[nb] += __shfl_xor(psum[nb], 32, 64);
    float rl = 1.0f / psum[nb];
    int qg = qblk + w * 32 + nb * 16 + l15;
#pragma unroll
    for (int mb = 0; mb < 4; ++mb)
#pragma unroll
      for (int r = 0; r < 4; ++r) {
        int hd = mb * 16 + quad * 4 + r;
        zb[((size_t)bh * 2048 + qg) * 64 + hd] = f2bf(o[mb][nb][r] * rl);
      }
  }
}

// ---------------------------------------------------------------------------
// Residual + LayerNorm with the reference's scrambled .view(b,s,-1) remap
// ---------------------------------------------------------------------------
__global__ __launch_bounds__(256) void ln_kernel(const float* __restrict__ emb,
                                                 const ushort_t* __restrict__ zb,
                                                 const float* __restrict__ gamma,
                                                 const float* __restrict__ beta,
                                                 float* __restrict__ out) {
  __shared__ float red[2][4];
  int row = blockIdx.x;
  int b = row >> 11, s = row & 2047;
  int h = s >> 7;
  int siHi = (s & 127) << 4;
  int tid = threadIdx.x;
  int dcol = tid * 4;
  int si = siHi | (dcol >> 6);
  int j = dcol & 63;

  f32x4 e4 = *(const f32x4*)(emb + (size_t)row * 1024 + dcol);
  us4 z4 = *(const us4*)(zb + (((size_t)(b * 16 + h) * 2048 + si) * 64 + j));
  float x0 = e4[0] + bf2f(z4.u[0]);
  float x1 = e4[1] + bf2f(z4.u[1]);
  float x2 = e4[2] + bf2f(z4.u[2]);
  float x3 = e4[3] + bf2f(z4.u[3]);

  float sum = x0 + x1 + x2 + x3;
  float sq  = x0 * x0 + x1 * x1 + x2 * x2 + x3 * x3;
#pragma unroll
  for (int off = 1; off <= 32; off <<= 1) {
    sum += __shfl_xor(sum, off, 64);
    sq  += __shfl_xor(sq,  off, 64);
  }
  int wv = tid >> 6;
  if ((tid & 63) == 0) { red[0][wv] = sum; red[1][wv] = sq; }
  __syncthreads();
  float ts = red[0][0] + red[0][1] + red[0][2] + red[0][3];
  float tq = red[1][0] + red[1][1] + red[1][2] + red[1][3];
  float mu = ts * (1.0f / 1024.0f);
  float var = tq * (1.0f / 1024.0f) - mu * mu;
  float rsig = rsqrtf(var + 1e-5f);

  f32x4 g4 = *(const f32x4*)(gamma + dcol);
  f32x4 b4 = *(const f32x4*)(beta + dcol);
  f32x4 o4;
  o4[0] = (x0 - mu) * rsig * g4[0] + b4[0];
  o4[1] = (x1 - mu) * rsig * g4[1] + b4[1];
  o4[2] = (x2 - mu) * rsig * g4[2] + b4[2];
  o4[3] = (x3 - mu) * rsig * g4[3] + b4[3];
  *(f32x4*)(out + (size_t)row * 1024 + dcol) = o4;
}

// ---------------------------------------------------------------------------
extern "C" void kernel_launch(void* const* d_in, const int* in_sizes, int n_in,
                              void* d_out, int out_size, void* d_ws, size_t ws_size,
                              hipStream_t stream) {
  (void)in_sizes; (void)n_in; (void)out_size; (void)ws_size;
  const float* emb   = (const float*)d_in[0];
  const float* Wq    = (const float*)d_in[1];
  const float* bq    = (const float*)d_in[2];
  const float* Wk    = (const float*)d_in[3];
  const float* bk    = (const float*)d_in[4];
  const float* Wv    = (const float*)d_in[5];
  const float* bv    = (const float*)d_in[6];
  const float* gamma = (const float*)d_in[7];
  const float* beta  = (const float*)d_in[8];
  float* out = (float*)d_out;

  char* ws = (char*)d_ws;
  ushort_t* Xbf  = (ushort_t*)(ws);                    // 8,388,608 B
  ushort_t* Wqb  = (ushort_t*)(ws + 8388608);          // 2,097,152 B each
  ushort_t* Wkb  = (ushort_t*)(ws + 10485760);
  ushort_t* Wvb  = (ushort_t*)(ws + 12582912);
  ushort_t* qbuf = (ushort_t*)(ws + 14680064);         // 8,388,608 B
  ushort_t* kbuf = (ushort_t*)(ws + 23068672);         // 8,388,608 B (hd-swizzled)
  ushort_t* vbuf = (ushort_t*)(ws + 31457280);         // bf16 V (consumed by tr)
  ushort_t* zbuf = (ushort_t*)(ws + 31457280);         // aliases vbuf (attn output)
  uchar_t*  vTb  = (uchar_t*)(ws + 39845888);          // 4,194,304 B fp8 V^T (key-swizzled)

  cvt_kernel<<<4096, 256, 0, stream>>>(emb, Xbf, 4194304);
  cvt_kernel<<<1024, 256, 0, stream>>>(Wq, Wqb, 1048576);
  cvt_kernel<<<1024, 256, 0, stream>>>(Wk, Wkb, 1048576);
  cvt_kernel<<<1024, 256, 0, stream>>>(Wv, Wvb, 1048576);

  QkvArgs a;
  a.X = Xbf;
  a.W0 = Wqb; a.W1 = Wkb; a.W2 = Wvb;
  a.b0 = bq;  a.b1 = bk;  a.b2 = bv;
  a.o0 = qbuf; a.o1 = kbuf; a.o2 = vbuf;
  qkv_gemm<<<dim3(32, 8, 3), 256, 0, stream>>>(a);

  tr_kernel<<<dim3(32, 32), 256, 0, stream>>>(vbuf, vTb);

  attn_kernel<<<dim3(16, 32), 256, 0, stream>>>(qbuf, kbuf, vTb, zbuf);

  ln_kernel<<<4096, 256, 0, stream>>>(emb, zbuf, gamma, beta, out);
}

// Round 11
// 201.389 us; speedup vs baseline: 1.1302x; 1.1302x over previous
//
#include <hip/hip_runtime.h>
#include <hip/hip_bf16.h>
#include <math.h>

// Problem constants: B=2, S=2048, D=1024, H=16, HD=64
typedef unsigned short ushort_t;
typedef unsigned char uchar_t;
typedef __attribute__((ext_vector_type(8))) short short8;   // 8 bf16 = 4 VGPRs (MFMA A/B frag)
typedef __attribute__((ext_vector_type(4))) float f32x4;    // MFMA C/D frag

struct __align__(8) us4 { ushort_t u[4]; };

__device__ __forceinline__ ushort_t f2bf(float x) {
  union { float f; unsigned u; } c; c.f = x;
  unsigned r = c.u + 0x7FFFu + ((c.u >> 16) & 1u);  // RNE
  return (ushort_t)(r >> 16);
}
__device__ __forceinline__ float bf2f(ushort_t b) {
  union { unsigned u; float f; } c; c.u = ((unsigned)b) << 16;
  return c.f;
}

// ---------------------------------------------------------------------------
// Fused fp32 -> bf16 convert for X + Wq + Wk + Wv (one launch).
// Uniform scalar branch pointer select; grid exactly covers all elements.
// ---------------------------------------------------------------------------
struct CvtArgs {
  const float* s0; const float* s1; const float* s2; const float* s3;
  ushort_t* d0; ushort_t* d1; ushort_t* d2; ushort_t* d3;
};

__global__ __launch_bounds__(256) void cvt4_kernel(CvtArgs a) {
  int blk = blockIdx.x;
  const float* src; ushort_t* dst; int off;
  if (blk < 4096)      { src = a.s0; dst = a.d0; off = blk; }
  else if (blk < 5120) { src = a.s1; dst = a.d1; off = blk - 4096; }
  else if (blk < 6144) { src = a.s2; dst = a.d2; off = blk - 5120; }
  else                 { src = a.s3; dst = a.d3; off = blk - 6144; }
  int idx = (off * 256 + threadIdx.x) * 4;
  f32x4 v = *(const f32x4*)(src + idx);
  us4 o;
  o.u[0] = f2bf(v[0]); o.u[1] = f2bf(v[1]); o.u[2] = f2bf(v[2]); o.u[3] = f2bf(v[3]);
  *(us4*)(dst + idx) = o;
}

// ---------------------------------------------------------------------------
// QKV projection GEMM (m97 structure).
//  z==0 (Q): bf16 linear [bh][s][hd].
//  z==1 (K): bf16, hd-unit XOR swizzle: hd' = ((hd>>3)^(s&7))*8+(hd&7).
//  z==2 (V): fp8 e4m3 TRANSPOSED [bh][hd][key] with key-unit swizzle
//            (exact tr_kernel output layout, emitted directly):
//            addr = page + hd*2048 + (s&~127) + ((((s>>4)&7)^(hd&7))<<4) + (s&15)
// ---------------------------------------------------------------------------
struct QkvArgs {
  const ushort_t* X;
  const ushort_t* W0; const ushort_t* W1; const ushort_t* W2;
  const float* b0; const float* b1; const float* b2;
  ushort_t* oQ; ushort_t* oK; uchar_t* oV;
};

__global__ __launch_bounds__(256) void qkv_gemm(QkvArgs a) {
  __shared__ __align__(16) ushort_t As[128 * 32];
  __shared__ __align__(16) ushort_t Bs[128 * 32];
  const int z = blockIdx.z;
  const ushort_t* W  = (z == 0) ? a.W0 : ((z == 1) ? a.W1 : a.W2);
  const float* bias  = (z == 0) ? a.b0 : ((z == 1) ? a.b1 : a.b2);
  const int mBase = blockIdx.x * 128;
  const int nBase = blockIdx.y * 128;
  const int tid  = threadIdx.x;
  const int lane = tid & 63;
  const int w    = tid >> 6;
  const int wm   = w >> 1, wn = w & 1;
  const int quad = lane >> 4;
  const int l15  = lane & 15;

  f32x4 acc[4][4] = {};

  const int srow = lane >> 2;
  const int scol = (lane & 3) * 8;
  const ushort_t* gA0 = a.X + (mBase + srow) * 1024 + scol;
  const ushort_t* gB0 = W   + (nBase + srow) * 1024 + scol;

  for (int k0 = 0; k0 < 1024; k0 += 32) {
#pragma unroll
    for (int p = 0; p < 2; ++p) {
      int rr = (w * 2 + p) * 16;
      __builtin_amdgcn_global_load_lds(
          (const __attribute__((address_space(1))) void*)(gA0 + rr * 1024 + k0),
          (__attribute__((address_space(3))) void*)(As + (w * 2 + p) * 512), 16, 0, 0);
      __builtin_amdgcn_global_load_lds(
          (const __attribute__((address_space(1))) void*)(gB0 + rr * 1024 + k0),
          (__attribute__((address_space(3))) void*)(Bs + (w * 2 + p) * 512), 16, 0, 0);
    }
    __syncthreads();
    short8 af[4], bfr[4];
#pragma unroll
    for (int mi = 0; mi < 4; ++mi)
      af[mi] = *(const short8*)(As + (wm * 64 + mi * 16 + l15) * 32 + quad * 8);
#pragma unroll
    for (int ni = 0; ni < 4; ++ni)
      bfr[ni] = *(const short8*)(Bs + (wn * 64 + ni * 16 + l15) * 32 + quad * 8);
#pragma unroll
    for (int mi = 0; mi < 4; ++mi)
#pragma unroll
      for (int ni = 0; ni < 4; ++ni)
        acc[mi][ni] = __builtin_amdgcn_mfma_f32_16x16x32_bf16(af[mi], bfr[ni], acc[mi][ni], 0, 0, 0);
    __syncthreads();
  }

  if (z < 2) {
    ushort_t* out = (z == 0) ? a.oQ : a.oK;
    const int swz = (z == 1) ? 7 : 0;
#pragma unroll
    for (int ni = 0; ni < 4; ++ni) {
      int n = nBase + wn * 64 + ni * 16 + l15;
      float bv = bias[n];
      int h = n >> 6, hd = n & 63;
      int hdHi = hd >> 3, hdLo = hd & 7;
#pragma unroll
      for (int mi = 0; mi < 4; ++mi) {
        int m0 = mBase + wm * 64 + mi * 16 + quad * 4;
#pragma unroll
        for (int r = 0; r < 4; ++r) {
          int m = m0 + r;
          int bb = m >> 11, s = m & 2047;
          int hdw = (((hdHi ^ (s & swz)) << 3) | hdLo);
          out[((bb * 16 + h) * 2048 + s) * 64 + hdw] = f2bf(acc[mi][ni][r] + bv);
        }
      }
    }
  } else {
    // V: fp8 transposed + key-swizzled store (4 consecutive keys per dword)
#pragma unroll
    for (int ni = 0; ni < 4; ++ni) {
      int n = nBase + wn * 64 + ni * 16 + l15;
      float bv = bias[n];
      int h = n >> 6, hd = n & 63;
#pragma unroll
      for (int mi = 0; mi < 4; ++mi) {
        int m0 = mBase + wm * 64 + mi * 16 + quad * 4;
        int bb = m0 >> 11, s0 = m0 & 2047;
        unsigned int pk = __builtin_amdgcn_cvt_pk_fp8_f32(acc[mi][ni][0] + bv, acc[mi][ni][1] + bv, 0, false);
        pk = __builtin_amdgcn_cvt_pk_fp8_f32(acc[mi][ni][2] + bv, acc[mi][ni][3] + bv, pk, true);
        size_t addr = (size_t)(bb * 16 + h) * 131072 + hd * 2048 +
                      (s0 & ~127) + ((((s0 >> 4) & 7) ^ (hd & 7)) << 4) + (s0 & 15);
        *(unsigned int*)(a.oV + addr) = pk;
      }
    }
  }
}

// ---------------------------------------------------------------------------
// Attention (round-7 green source VERBATIM — tile-128, single-buffer staging,
// builtin exp2(s*cexp), fp8 P/V, post-softmax anti-causal mask).
// ---------------------------------------------------------------------------
__global__ __launch_bounds__(256) void attn_kernel(const ushort_t* __restrict__ qb,
                                                   const ushort_t* __restrict__ kb,
                                                   const uchar_t* __restrict__ vT,
                                                   ushort_t* __restrict__ zb) {
  __shared__ __align__(16) ushort_t Ks[128 * 64];   // [key][hd] swizzled bf16
  __shared__ __align__(16) uchar_t  Vt[64 * 128];   // [hd][key] swizzled fp8
  __shared__ __align__(16) uchar_t  Ps[128 * 128];  // [q][key]  swizzled fp8 (wave-private rows)
  const int bh   = blockIdx.y;
  const int qblk = blockIdx.x * 128;
  const int tid  = threadIdx.x;
  const int lane = tid & 63;
  const int w    = tid >> 6;
  const int quad = lane >> 4;
  const int l15  = lane & 15;
  const int l7   = l15 & 7;
  const float cexp = 0.02209708691f * 1.44269504089f;  // (1/sqrt(2048)) * log2(e)

  const ushort_t* qpage = qb + (size_t)bh * (2048 * 64);
  const ushort_t* kpage = kb + (size_t)bh * (2048 * 64);
  const uchar_t*  vpage = vT + (size_t)bh * (64 * 2048);

  // Q fragments (constant across key tiles; Q global layout is linear)
  short8 qf[2][2];
#pragma unroll
  for (int nb = 0; nb < 2; ++nb) {
    int qg = qblk + w * 32 + nb * 16 + l15;
#pragma unroll
    for (int kd = 0; kd < 2; ++kd)
      qf[nb][kd] = *(const short8*)(qpage + (size_t)qg * 64 + kd * 32 + quad * 8);
  }

  float psum[2] = {0.f, 0.f};
  f32x4 o[4][2] = {};  // O^T: [hd block][q block]

  for (int kt = 0; kt < 2048; kt += 128) {
    const bool needV = (kt + 127 >= qblk);            // block-uniform
    const bool needP = (kt + 127 >= qblk + w * 32);   // wave-uniform
    __syncthreads();  // prior tile's LDS reads complete before DMA overwrite

    // ---- async stage K tile (16 KB, 4 chunks/wave) ----
#pragma unroll
    for (int p = 0; p < 4; ++p) {
      int j = w * 4 + p;
      __builtin_amdgcn_global_load_lds(
          (const __attribute__((address_space(1))) void*)(kpage + (size_t)kt * 64 + j * 512 + lane * 8),
          (__attribute__((address_space(3))) void*)(Ks + j * 512), 16, 0, 0);
    }
    // ---- async stage V^T tile (8 KB fp8, 2 chunks/wave) ----
    if (needV) {
#pragma unroll
      for (int p = 0; p < 2; ++p) {
        int j = w * 2 + p;
        __builtin_amdgcn_global_load_lds(
            (const __attribute__((address_space(1))) void*)(vpage + (size_t)(j * 8 + (lane >> 3)) * 2048 + kt + (lane & 7) * 16),
            (__attribute__((address_space(3))) void*)(Vt + j * 1024), 16, 0, 0);
      }
    }
    __syncthreads();  // drain vmcnt -> staged data visible

    // ---- S^T = K*Q^T per 16-key slice; exp + psum + fp8 P pack ----
#pragma unroll
    for (int mb = 0; mb < 8; ++mb) {
      const ushort_t* krow = Ks + (mb * 16 + l15) * 64;
      short8 kf0 = *(const short8*)(krow + ((0 + quad) ^ l7) * 8);
      short8 kf1 = *(const short8*)(krow + ((4 + quad) ^ l7) * 8);
      f32x4 s0 = {}, s1 = {};
      s0 = __builtin_amdgcn_mfma_f32_16x16x32_bf16(kf0, qf[0][0], s0, 0, 0, 0);
      s0 = __builtin_amdgcn_mfma_f32_16x16x32_bf16(kf1, qf[0][1], s0, 0, 0, 0);
      s1 = __builtin_amdgcn_mfma_f32_16x16x32_bf16(kf0, qf[1][0], s1, 0, 0, 0);
      s1 = __builtin_amdgcn_mfma_f32_16x16x32_bf16(kf1, qf[1][1], s1, 0, 0, 0);
      const int keyb = kt + mb * 16 + quad * 4;
#pragma unroll
      for (int nb = 0; nb < 2; ++nb) {
        f32x4 s = nb ? s1 : s0;
        float p0 = __builtin_amdgcn_exp2f(s[0] * cexp);
        float p1 = __builtin_amdgcn_exp2f(s[1] * cexp);
        float p2 = __builtin_amdgcn_exp2f(s[2] * cexp);
        float p3 = __builtin_amdgcn_exp2f(s[3] * cexp);
        psum[nb] += (p0 + p1) + (p2 + p3);  // denominator: ALL keys (mask is post-softmax)
        if (needP) {
          int qg = qblk + w * 32 + nb * 16 + l15;
          float m0 = (keyb + 0 >= qg) ? p0 : 0.f;
          float m1 = (keyb + 1 >= qg) ? p1 : 0.f;
          float m2 = (keyb + 2 >= qg) ? p2 : 0.f;
          float m3 = (keyb + 3 >= qg) ? p3 : 0.f;
          unsigned int pk = __builtin_amdgcn_cvt_pk_fp8_f32(m0, m1, 0, false);
          pk = __builtin_amdgcn_cvt_pk_fp8_f32(m2, m3, pk, true);
          *(unsigned int*)(Ps + (w * 32 + nb * 16 + l15) * 128 + ((mb ^ l7) * 16) + quad * 4) = pk;
        }
      }
    }

    // ---- O^T += V^T * P^T in fp8 (skip fully-masked tiles) ----
    if (needP) {
#pragma unroll
      for (int kd = 0; kd < 4; ++kd) {
        const int un = ((kd * 2 + (quad >> 1)) ^ l7) * 16 + (quad & 1) * 8;
        long long pf0 = *(const long long*)(Ps + (w * 32 + l15) * 128 + un);
        long long pf1 = *(const long long*)(Ps + (w * 32 + 16 + l15) * 128 + un);
#pragma unroll
        for (int mb = 0; mb < 4; ++mb) {
          long long vf = *(const long long*)(Vt + (mb * 16 + l15) * 128 + un);
          o[mb][0] = __builtin_amdgcn_mfma_f32_16x16x32_fp8_fp8(vf, pf0, o[mb][0], 0, 0, 0);
          o[mb][1] = __builtin_amdgcn_mfma_f32_16x16x32_fp8_fp8(vf, pf1, o[mb][1], 0, 0, 0);
        }
      }
    }
  }

  // ---- final denominator reduce (across quads) + store ----
#pragma unroll
  for (int nb = 0; nb < 2; ++nb) {
    psum[nb] += __shfl_xor(psum[nb], 16, 64);
    psum[nb] += __shfl_xor(psum[nb], 32, 64);
    float rl = 1.0f / psum[nb];
    int qg = qblk + w * 32 + nb * 16 + l15;
#pragma unroll
    for (int mb = 0; mb < 4; ++mb)
#pragma unroll
      for (int r = 0; r < 4; ++r) {
        int hd = mb * 16 + quad * 4 + r;
        zb[((size_t)bh * 2048 + qg) * 64 + hd] = f2bf(o[mb][nb][r] * rl);
      }
  }
}

// ---------------------------------------------------------------------------
// Residual + LayerNorm with the reference's scrambled .view(b,s,-1) remap
// ---------------------------------------------------------------------------
__global__ __launch_bounds__(256) void ln_kernel(const float* __restrict__ emb,
                                                 const ushort_t* __restrict__ zb,
                                                 const float* __restrict__ gamma,
                                                 const float* __restrict__ beta,
                                                 float* __restrict__ out) {
  __shared__ float red[2][4];
  int row = blockIdx.x;
  int b = row >> 11, s = row & 2047;
  int h = s >> 7;
  int siHi = (s & 127) << 4;
  int tid = threadIdx.x;
  int dcol = tid * 4;
  int si = siHi | (dcol >> 6);
  int j = dcol & 63;

  f32x4 e4 = *(const f32x4*)(emb + (size_t)row * 1024 + dcol);
  us4 z4 = *(const us4*)(zb + (((size_t)(b * 16 + h) * 2048 + si) * 64 + j));
  float x0 = e4[0] + bf2f(z4.u[0]);
  float x1 = e4[1] + bf2f(z4.u[1]);
  float x2 = e4[2] + bf2f(z4.u[2]);
  float x3 = e4[3] + bf2f(z4.u[3]);

  float sum = x0 + x1 + x2 + x3;
  float sq  = x0 * x0 + x1 * x1 + x2 * x2 + x3 * x3;
#pragma unroll
  for (int off = 1; off <= 32; off <<= 1) {
    sum += __shfl_xor(sum, off, 64);
    sq  += __shfl_xor(sq,  off, 64);
  }
  int wv = tid >> 6;
  if ((tid & 63) == 0) { red[0][wv] = sum; red[1][wv] = sq; }
  __syncthreads();
  float ts = red[0][0] + red[0][1] + red[0][2] + red[0][3];
  float tq = red[1][0] + red[1][1] + red[1][2] + red[1][3];
  float mu = ts * (1.0f / 1024.0f);
  float var = tq * (1.0f / 1024.0f) - mu * mu;
  float rsig = rsqrtf(var + 1e-5f);

  f32x4 g4 = *(const f32x4*)(gamma + dcol);
  f32x4 b4 = *(const f32x4*)(beta + dcol);
  f32x4 o4;
  o4[0] = (x0 - mu) * rsig * g4[0] + b4[0];
  o4[1] = (x1 - mu) * rsig * g4[1] + b4[1];
  o4[2] = (x2 - mu) * rsig * g4[2] + b4[2];
  o4[3] = (x3 - mu) * rsig * g4[3] + b4[3];
  *(f32x4*)(out + (size_t)row * 1024 + dcol) = o4;
}

// ---------------------------------------------------------------------------
extern "C" void kernel_launch(void* const* d_in, const int* in_sizes, int n_in,
                              void* d_out, int out_size, void* d_ws, size_t ws_size,
                              hipStream_t stream) {
  (void)in_sizes; (void)n_in; (void)out_size; (void)ws_size;
  const float* emb   = (const float*)d_in[0];
  const float* Wq    = (const float*)d_in[1];
  const float* bq    = (const float*)d_in[2];
  const float* Wk    = (const float*)d_in[3];
  const float* bk    = (const float*)d_in[4];
  const float* Wv    = (const float*)d_in[5];
  const float* bv    = (const float*)d_in[6];
  const float* gamma = (const float*)d_in[7];
  const float* beta  = (const float*)d_in[8];
  float* out = (float*)d_out;

  char* ws = (char*)d_ws;
  ushort_t* Xbf  = (ushort_t*)(ws);                    // 8,388,608 B
  ushort_t* Wqb  = (ushort_t*)(ws + 8388608);          // 2,097,152 B each
  ushort_t* Wkb  = (ushort_t*)(ws + 10485760);
  ushort_t* Wvb  = (ushort_t*)(ws + 12582912);
  ushort_t* qbuf = (ushort_t*)(ws + 14680064);         // 8,388,608 B
  ushort_t* kbuf = (ushort_t*)(ws + 23068672);         // 8,388,608 B (hd-swizzled)
  uchar_t*  vTb  = (uchar_t*)(ws + 31457280);          // 4,194,304 B fp8 V^T (key-swizzled)
  ushort_t* zbuf = (ushort_t*)(ws + 35651584);         // 8,388,608 B -> total 44,040,192 B

  CvtArgs c;
  c.s0 = emb; c.s1 = Wq; c.s2 = Wk; c.s3 = Wv;
  c.d0 = Xbf; c.d1 = Wqb; c.d2 = Wkb; c.d3 = Wvb;
  cvt4_kernel<<<7168, 256, 0, stream>>>(c);

  QkvArgs a;
  a.X = Xbf;
  a.W0 = Wqb; a.W1 = Wkb; a.W2 = Wvb;
  a.b0 = bq;  a.b1 = bk;  a.b2 = bv;
  a.oQ = qbuf; a.oK = kbuf; a.oV = vTb;
  qkv_gemm<<<dim3(32, 8, 3), 256, 0, stream>>>(a);

  attn_kernel<<<dim3(16, 32), 256, 0, stream>>>(qbuf, kbuf, vTb, zbuf);

  ln_kernel<<<4096, 256, 0, stream>>>(emb, zbuf, gamma, beta, out);
}